// Round 10
// baseline (231.062 us; speedup 1.0000x reference)
//
#include <hip/hip_runtime.h>
#include <math.h>

#define Dd 128
#define Tt 1024
#define Kk 2048
#define Nn 65536
#define DT 131072  // Dd*Tt

typedef __attribute__((ext_vector_type(8))) short short8;
typedef __attribute__((ext_vector_type(4))) float float4v;

// ws layout (bytes):
//   cbh     @ 0        : ushort[262144] = 524288   (bf16 hi plane of codebook, SOA-fragment layout)
//   e2f     @ 524288   : float[2048]    = 8192     (np-replica fp32 ||e||^2)
//   Arow    @ 532480   : float[65536]   = 262144   (np-replica fp32 ||x||^2, written by score_kernel)
//   idxbuf  @ 794624   : int[65536]     = 262144
//   counts  @ 1056768  : int[2048]      = 8192
//   part    @ 1064960  : double[512]    = 4096
//   cand_g  @ 1069056  : ushort[65536*16] = 2097152
//   candcnt @ 3166208  : int[65536]     = 262144
// total 3428352 B (~3.43 MB)
//
// cbh SOA layout: for code k, 16B granule g (g of the 256B row):
//   chunk=k>>6, ct=(k>>4)&3, col=k&15, ks=g>>2, quad=g&3
//   byte dest = chunk*16384 + ct*4096 + ks*1024 + quad*256 + col*16
// => per-(chunk,ct,ks) B-fragment load is lane*16B contiguous (1 KB).

// Setup: SOA bf16-hi split of codebook (blocks 0..127) + np-replica fp32
// ||e||^2 / counts-zero (blocks 128..135).
__global__ __launch_bounds__(256)
void setup_kernel(const float* __restrict__ cb, ushort* __restrict__ cbh,
                  float* __restrict__ e2f, int* __restrict__ counts) {
  const int bid = blockIdx.x, tid = threadIdx.x;
  if (bid < 128) {
    const int gi = bid * 256 + tid;               // 32768 granules (16B each)
    const int k = gi >> 4, g = gi & 15;
    const float* p = cb + (size_t)k * Dd + g * 8; // 32B coalesced read
    short8 w;
    #pragma unroll
    for (int j = 0; j < 8; ++j) {
      const unsigned u = __float_as_uint(p[j]);
      const unsigned hb = (u + 0x7FFFu + ((u >> 16) & 1u)) & 0xFFFF0000u;  // RNE bf16
      w[j] = (short)(hb >> 16);
    }
    const int chunk = k >> 6, ctc = (k >> 4) & 3, colc = k & 15;
    *(short8*)((char*)cbh + chunk * 16384 + ctc * 4096 + (g >> 2) * 1024 +
               (g & 3) * 256 + colc * 16) = w;
  } else {
    const int k = (bid - 128) * 256 + tid;        // 2048 codes
    counts[k] = 0;
    const float* p = cb + (size_t)k * Dd;
    float r[8];
    #pragma unroll
    for (int j = 0; j < 8; ++j) r[j] = __fmul_rn(p[j], p[j]);
    for (int i = 1; i < 16; ++i) {
      #pragma unroll
      for (int j = 0; j < 8; ++j) {
        const float v = p[8 * i + j];
        r[j] = __fadd_rn(r[j], __fmul_rn(v, v));
      }
    }
    e2f[k] = __fadd_rn(__fadd_rn(__fadd_rn(r[0], r[1]), __fadd_rn(r[2], r[3])),
                       __fadd_rn(__fadd_rn(r[4], r[5]), __fadd_rn(r[6], r[7])));
  }
}

// Phase 1: two-sweep hi-plane bf16 MFMA scoring, CHUNK-PER-WAVE structure.
// 64 rows/block (1024 blocks), 4 waves. Per round r8 (8 rounds/sweep), wave
// wv processes chunk r8*4+wv ENTIRELY: 64 rows x 64 cols = 64 MFMAs fed by
// 16 global B-loads (coalesced 1KB each) and 16 A-fragments. Each A value is
// loaded once and immediately consumed by 4 MFMAs (ct=0..3) -> even if the
// allocator remats afr from LDS (rounds 6-9 pathology: it always does), the
// DS traffic is 16 reads per 64 MFMAs = 4x under the MFMA pipe. Structure is
// insensitive to the allocator's residency choice -> MFMA-bound by design.
// Sweep A: per-lane min -> shfl over 16 cols -> LDS reduce over 4 waves ->
// exact row-global min m. Sweep B: bitwise-identical recompute, append codes
// with s < m + marg_row (marg_row = 8.7e-5*sqrt(Arow)+1e-4). Cap 16;
// candcnt>16 or 0 -> exact fallback (expected: none).
__global__ __launch_bounds__(256, 2)
void score_kernel(const float* __restrict__ z, const ushort* __restrict__ cbh,
                  const float* __restrict__ e2f, float* __restrict__ Arow,
                  ushort* __restrict__ cand_g, int* __restrict__ candcnt) {
  __shared__ __attribute__((aligned(16))) ushort zh[8192]; // 16KB z hi plane (64x128)
  __shared__ float margL[64];
  __shared__ float sredA[256];       // [row][wv]
  __shared__ float thrF[64];
  __shared__ int cntL[64];
  __shared__ ushort candL[64 * 16];  // 2KB

  const int tid = threadIdx.x;
  const int n0 = blockIdx.x * 64;                // 1024 blocks
  const int b = n0 >> 10, t0 = n0 & 1023;
  const float* zb = z + (size_t)b * DT + t0;
  const int lane = tid & 63, wv = tid >> 6;
  const int col = lane & 15, quad = lane >> 4;

  // ---- prologue: stage z hi plane (64 rows x 128 d, 16B-granule swizzled) ----
  {
    const int i = tid & 63;           // row in block
    const int half = tid >> 6;        // 0..3
    #pragma unroll
    for (int g4 = 0; g4 < 4; ++g4) {
      const int gran = half * 4 + g4;
      short8 w;
      #pragma unroll
      for (int j = 0; j < 8; ++j) {
        const int d = gran * 8 + j;
        const float v = zb[d * Tt + i];            // coalesced over i
        const unsigned u = __float_as_uint(v);
        const unsigned hb = (u + 0x7FFFu + ((u >> 16) & 1u)) & 0xFFFF0000u;
        w[j] = (short)(hb >> 16);
      }
      *(short8*)&zh[i * 128 + ((gran ^ (i & 15)) << 3)] = w;
    }
  }
  // ---- Arow: np-pairwise fp32 ||x||^2 (bitwise = reference pass; z L1-hot) ----
  if (tid < 64) {
    const float* p = zb + tid;                    // x_d = p[d*Tt]
    float r[8];
    #pragma unroll
    for (int j = 0; j < 8; ++j) {
      const float v = p[j * Tt];
      r[j] = __fmul_rn(v, v);
    }
    for (int i = 1; i < 16; ++i) {
      #pragma unroll
      for (int j = 0; j < 8; ++j) {
        const float v = p[(8 * i + j) * Tt];
        r[j] = __fadd_rn(r[j], __fmul_rn(v, v));
      }
    }
    const float A = __fadd_rn(__fadd_rn(__fadd_rn(r[0], r[1]), __fadd_rn(r[2], r[3])),
                              __fadd_rn(__fadd_rn(r[4], r[5]), __fadd_rn(r[6], r[7])));
    Arow[n0 + tid] = A;
    margL[tid] = 8.7e-5f * sqrtf(A) + 1.0e-4f;
    cntL[tid] = 0;
  }
  __syncthreads();

  // ---- A fragments (remat from zh is fine: 1 read feeds 4 MFMAs) ----
  short8 afr[16];
  #pragma unroll
  for (int rt = 0; rt < 4; ++rt)
    #pragma unroll
    for (int ks = 0; ks < 4; ++ks) {
      const int rw = rt * 16 + col;               // rw&15 == col
      afr[rt * 4 + ks] = *(const short8*)&zh[rw * 128 + (((ks * 4 + quad) ^ col) << 3)];
    }

  // per-lane B base in SOA layout (ushort units): chunk*8192 + ct*2048 +
  // ks*512 + lane*8
  const ushort* const bpL = cbh + lane * 8;
  const float4v vzero = {0.f, 0.f, 0.f, 0.f};
  float rmin[16];
  #pragma unroll
  for (int sl = 0; sl < 16; ++sl) rmin[sl] = 1e30f;

  // ---- Sweep A: exact row-global min (barrier-free, chunk-per-wave) ----
  for (int r8 = 0; r8 < 8; ++r8) {
    const int chunk = r8 * 4 + wv;
    const ushort* bp = bpL + (size_t)chunk * 8192;
    short8 bb[4][4];
    #pragma unroll
    for (int ct = 0; ct < 4; ++ct)
      #pragma unroll
      for (int ks = 0; ks < 4; ++ks)
        bb[ct][ks] = *(const short8*)(bp + ct * 2048 + ks * 512);
    const int cb0 = chunk * 64 + col;
    float e2v[4];
    #pragma unroll
    for (int ct = 0; ct < 4; ++ct) e2v[ct] = e2f[cb0 + ct * 16];
    float4v acc[4][4];                            // [rt][ct]
    #pragma unroll
    for (int rt = 0; rt < 4; ++rt)
      #pragma unroll
      for (int ct = 0; ct < 4; ++ct) acc[rt][ct] = vzero;
    #pragma unroll
    for (int rt = 0; rt < 4; ++rt)
      #pragma unroll
      for (int ks = 0; ks < 4; ++ks) {
        const short8 a = afr[rt * 4 + ks];        // 1 load : 4 MFMAs
        acc[rt][0] = __builtin_amdgcn_mfma_f32_16x16x32_bf16(a, bb[0][ks], acc[rt][0], 0, 0, 0);
        acc[rt][1] = __builtin_amdgcn_mfma_f32_16x16x32_bf16(a, bb[1][ks], acc[rt][1], 0, 0, 0);
        acc[rt][2] = __builtin_amdgcn_mfma_f32_16x16x32_bf16(a, bb[2][ks], acc[rt][2], 0, 0, 0);
        acc[rt][3] = __builtin_amdgcn_mfma_f32_16x16x32_bf16(a, bb[3][ks], acc[rt][3], 0, 0, 0);
      }
    #pragma unroll
    for (int rt = 0; rt < 4; ++rt)
      #pragma unroll
      for (int ct = 0; ct < 4; ++ct)
        #pragma unroll
        for (int r = 0; r < 4; ++r) {
          const float s = fmaf(-2.0f, acc[rt][ct][r], e2v[ct]);
          rmin[rt * 4 + r] = fminf(rmin[rt * 4 + r], s);
        }
  }

  // ---- exact row-global min reduce: 16 cols (shfl) x 4 waves (LDS) ----
  #pragma unroll
  for (int sl = 0; sl < 16; ++sl) {
    float v = rmin[sl];
    v = fminf(v, __shfl_xor(v, 1, 64));
    v = fminf(v, __shfl_xor(v, 2, 64));
    v = fminf(v, __shfl_xor(v, 4, 64));
    v = fminf(v, __shfl_xor(v, 8, 64));
    rmin[sl] = v;
  }
  if (col == 0) {
    #pragma unroll
    for (int sl = 0; sl < 16; ++sl) {
      const int rw = (sl >> 2) * 16 + quad * 4 + (sl & 3);
      sredA[rw * 4 + wv] = rmin[sl];
    }
  }
  __syncthreads();
  if (tid < 64) {
    const float m = fminf(fminf(sredA[tid * 4], sredA[tid * 4 + 1]),
                          fminf(sredA[tid * 4 + 2], sredA[tid * 4 + 3]));
    thrF[tid] = m + margL[tid];
  }
  __syncthreads();
  #pragma unroll
  for (int sl = 0; sl < 16; ++sl)       // reuse rmin regs as per-slot thresholds
    rmin[sl] = thrF[(sl >> 2) * 16 + quad * 4 + (sl & 3)];

  // ---- Sweep B: bitwise-identical recompute, exact-threshold append ----
  for (int r8 = 0; r8 < 8; ++r8) {
    const int chunk = r8 * 4 + wv;
    const ushort* bp = bpL + (size_t)chunk * 8192;
    short8 bb[4][4];
    #pragma unroll
    for (int ct = 0; ct < 4; ++ct)
      #pragma unroll
      for (int ks = 0; ks < 4; ++ks)
        bb[ct][ks] = *(const short8*)(bp + ct * 2048 + ks * 512);
    const int cb0 = chunk * 64 + col;
    float e2v[4];
    #pragma unroll
    for (int ct = 0; ct < 4; ++ct) e2v[ct] = e2f[cb0 + ct * 16];
    float4v acc[4][4];
    #pragma unroll
    for (int rt = 0; rt < 4; ++rt)
      #pragma unroll
      for (int ct = 0; ct < 4; ++ct) acc[rt][ct] = vzero;
    #pragma unroll
    for (int rt = 0; rt < 4; ++rt)
      #pragma unroll
      for (int ks = 0; ks < 4; ++ks) {
        const short8 a = afr[rt * 4 + ks];
        acc[rt][0] = __builtin_amdgcn_mfma_f32_16x16x32_bf16(a, bb[0][ks], acc[rt][0], 0, 0, 0);
        acc[rt][1] = __builtin_amdgcn_mfma_f32_16x16x32_bf16(a, bb[1][ks], acc[rt][1], 0, 0, 0);
        acc[rt][2] = __builtin_amdgcn_mfma_f32_16x16x32_bf16(a, bb[2][ks], acc[rt][2], 0, 0, 0);
        acc[rt][3] = __builtin_amdgcn_mfma_f32_16x16x32_bf16(a, bb[3][ks], acc[rt][3], 0, 0, 0);
      }
    #pragma unroll
    for (int rt = 0; rt < 4; ++rt)
      #pragma unroll
      for (int ct = 0; ct < 4; ++ct)
        #pragma unroll
        for (int r = 0; r < 4; ++r) {
          const float s = fmaf(-2.0f, acc[rt][ct][r], e2v[ct]);
          if (s < rmin[rt * 4 + r]) {
            const int rw = rt * 16 + quad * 4 + r;
            const int pos = atomicAdd(&cntL[rw], 1);
            if (pos < 16) candL[rw * 16 + pos] = (ushort)(cb0 + ct * 16);
          }
        }
  }
  __syncthreads();
  if (tid < 64) {
    const int n = n0 + tid;
    candcnt[n] = cntL[tid];
    uint4* dst = (uint4*)(cand_g + (size_t)n * 16);
    const uint4* src = (const uint4*)(candL + tid * 16);
    dst[0] = src[0];
    dst[1] = src[1];
  }
}

// Phase 2: exact np-replica rescore + f64 commitment-loss partial via
// loss_row = A - 2*dot_win + e2[win] (f64; dot already computed for winner).
__global__ __launch_bounds__(256)
void rescore_kernel(const float* __restrict__ z, const float* __restrict__ cb,
                    const float* __restrict__ e2f, const float* __restrict__ Arow,
                    const ushort* __restrict__ cand_g, const int* __restrict__ candcnt,
                    int* __restrict__ idxbuf, int* __restrict__ counts,
                    float* __restrict__ out_idx, double* __restrict__ part) {
  const int tid = threadIdx.x;
  const int n = blockIdx.x * 256 + tid;           // 256 blocks
  const int c = candcnt[n];
  double sq = 0.0;
  if (c >= 1 && c <= 16) {                        // fallback handles the rest
    const int b = n >> 10, t = n & 1023;
    const float* zb = z + (size_t)b * DT + t;
    const float A = Arow[n];
    float best = 1e30f;
    int bk = Kk;
    double bacc = 0.0;
    for (int j = 0; j < c; ++j) {
      const int k = cand_g[(size_t)n * 16 + j];
      const float* e = cb + (size_t)k * Dd;
      double acc = 0.0;
      #pragma unroll 8
      for (int d = 0; d < 128; d += 4) {
        const float4 ev = *(const float4*)(e + d);
        acc += (double)zb[(d + 0) * Tt] * (double)ev.x;
        acc += (double)zb[(d + 1) * Tt] * (double)ev.y;
        acc += (double)zb[(d + 2) * Tt] * (double)ev.z;
        acc += (double)zb[(d + 3) * Tt] * (double)ev.w;
      }
      const float m32 = (float)acc;
      const float X = __fsub_rn(A, __fmul_rn(2.0f, m32));
      const float Dq = __fadd_rn(X, e2f[k]);
      if (Dq < best || (Dq == best && k < bk)) { best = Dq; bk = k; bacc = acc; }
    }
    idxbuf[n] = bk;
    out_idx[n] = (float)bk;
    atomicAdd(&counts[bk], 1);
    sq = (double)A - 2.0 * bacc + (double)e2f[bk];
  }
  #pragma unroll
  for (int o = 32; o > 0; o >>= 1) sq += __shfl_down(sq, o, 64);
  __shared__ double w4[4];
  if ((tid & 63) == 0) w4[tid >> 6] = sq;
  __syncthreads();
  if (tid == 0) part[blockIdx.x] = w4[0] + w4[1] + w4[2] + w4[3];
}

// Fallback: full exact scan for rows with empty/overflowed lists (expected:
// none). Contributes those rows' loss into part[256..511].
__global__ __launch_bounds__(256)
void fallback_kernel(const float* __restrict__ z, const float* __restrict__ cb,
                     const float* __restrict__ e2f, const float* __restrict__ Arow,
                     const int* __restrict__ candcnt, int* __restrict__ idxbuf,
                     int* __restrict__ counts, float* __restrict__ out_idx,
                     double* __restrict__ part) {
  __shared__ int flags[256];
  __shared__ int nf;
  __shared__ float xrow[128];
  __shared__ float rs[256];
  __shared__ int rk[256];
  const int tid = threadIdx.x;
  const int nb = blockIdx.x * 256;                // 256 blocks
  if (tid == 0) { nf = 0; part[256 + blockIdx.x] = 0.0; }
  __syncthreads();
  const int c = candcnt[nb + tid];
  const int bad = (c < 1 || c > 16) ? 1 : 0;
  flags[tid] = bad;
  if (bad) atomicAdd(&nf, 1);
  __syncthreads();
  if (nf == 0) return;                            // fast path
  double bsum = 0.0;
  for (int rr = 0; rr < 256; ++rr) {
    if (!flags[rr]) continue;                     // block-uniform
    const int n = nb + rr;
    const int b = n >> 10, t = n & 1023;
    if (tid < 128) xrow[tid] = z[(size_t)b * DT + (size_t)tid * Tt + t];
    __syncthreads();
    const float A = Arow[n];
    float best = 1e30f;
    int bk = Kk;
    for (int kk = tid * 8; kk < tid * 8 + 8; ++kk) {
      const float* e = cb + (size_t)kk * Dd;
      double acc = 0.0;
      for (int d = 0; d < 128; d += 4) {
        const float4 ev = *(const float4*)(e + d);
        acc += (double)xrow[d + 0] * (double)ev.x;
        acc += (double)xrow[d + 1] * (double)ev.y;
        acc += (double)xrow[d + 2] * (double)ev.z;
        acc += (double)xrow[d + 3] * (double)ev.w;
      }
      const float m32 = (float)acc;
      const float Dq = __fadd_rn(__fsub_rn(A, __fmul_rn(2.0f, m32)), e2f[kk]);
      if (Dq < best || (Dq == best && kk < bk)) { best = Dq; bk = kk; }
    }
    rs[tid] = best;
    rk[tid] = bk;
    __syncthreads();
    for (int o = 128; o > 0; o >>= 1) {
      if (tid < o) {
        if (rs[tid + o] < rs[tid] || (rs[tid + o] == rs[tid] && rk[tid + o] < rk[tid])) {
          rs[tid] = rs[tid + o];
          rk[tid] = rk[tid + o];
        }
      }
      __syncthreads();
    }
    if (tid == 0) {
      const int w = rk[0];
      idxbuf[n] = w;
      out_idx[n] = (float)w;
      atomicAdd(&counts[w], 1);
      const float* ew = cb + (size_t)w * Dd;
      for (int d = 0; d < 128; ++d) {
        const double dif = (double)xrow[d] - (double)ew[d];
        bsum += dif * dif;
      }
    }
    __syncthreads();
  }
  if (tid == 0) part[256 + blockIdx.x] = bsum;
}

// Gather z_q into (B,D,T) layout, LDS-transpose version: stage 64 code-rows
// (16B-granule gathers, 4x fewer L1 transactions than per-element) into
// padded LDS, then write coalesced 256B runs per d-row.
__global__ __launch_bounds__(256)
void gather_kernel(const float* __restrict__ cb, const int* __restrict__ idxbuf,
                   float* __restrict__ out0) {
  __shared__ float ef[64 * 132];     // 33.8KB, stride 132 floats (16B-aligned)
  __shared__ int sidx[64];
  const int tid = threadIdx.x;
  const int n0 = blockIdx.x * 64;    // 1024 blocks; 64 consecutive t, same b
  const int b = n0 >> 10, t0 = n0 & 1023;
  if (tid < 64) sidx[tid] = idxbuf[n0 + tid];
  __syncthreads();
  {
    const int r = tid & 63, q = tid >> 6;         // wave q stages chunk q
    const float* src = cb + (size_t)sidx[r] * Dd + q * 32;
    float* dst = ef + r * 132 + q * 32;
    #pragma unroll
    for (int j = 0; j < 8; ++j)
      *(float4*)(dst + 4 * j) = *(const float4*)(src + 4 * j);
  }
  __syncthreads();
  {
    const int l = tid & 63, w = tid >> 6;         // wave w writes d = w*32..w*32+31
    float* ob = out0 + ((size_t)b << 17) + (size_t)(w * 32) * 1024 + t0 + l;
    #pragma unroll
    for (int i = 0; i < 32; ++i)
      ob[(size_t)i * 1024] = ef[l * 132 + w * 32 + i];
  }
}

__global__ __launch_bounds__(256)
void finalize_kernel(const int* __restrict__ counts, const double* __restrict__ part,
                     float* __restrict__ out) {
  const int tid = threadIdx.x;
  __shared__ double red[256];
  double s = 0.0;
  for (int i = tid; i < 512; i += 256) s += part[i];
  red[tid] = s;
  __syncthreads();
  for (int o = 128; o > 0; o >>= 1) {
    if (tid < o) red[tid] += red[tid + o];
    __syncthreads();
  }
  const double loss = red[0];
  __syncthreads();
  double e = 0.0;
  for (int k = tid; k < 2048; k += 256) {
    const double p = (double)counts[k] / 65536.0;
    e += p * log(p + 1e-10);
  }
  red[tid] = e;
  __syncthreads();
  for (int o = 128; o > 0; o >>= 1) {
    if (tid < o) red[tid] += red[tid + o];
    __syncthreads();
  }
  if (tid == 0) {
    out[8388608] = (float)(0.25 * loss / 8388608.0);
    out[8388609] = (float)exp(-red[0]);
  }
}

extern "C" void kernel_launch(void* const* d_in, const int* in_sizes, int n_in,
                              void* d_out, int out_size, void* d_ws, size_t ws_size,
                              hipStream_t stream) {
  const float* z = (const float*)d_in[0];      // (B, D, T) fp32
  const float* cb = (const float*)d_in[1];     // (K, D) fp32
  float* out = (float*)d_out;                  // [z_q (8388608) | loss | perp | idx (65536)]
  char* ws = (char*)d_ws;
  ushort* cbh    = (ushort*)ws;
  float* e2f     = (float*)(ws + 524288);
  float* Arow    = (float*)(ws + 532480);
  int* idxbuf    = (int*)(ws + 794624);
  int* counts    = (int*)(ws + 1056768);
  double* part   = (double*)(ws + 1064960);
  ushort* cand_g = (ushort*)(ws + 1069056);
  int* candcnt   = (int*)(ws + 3166208);

  hipLaunchKernelGGL(setup_kernel,    dim3(136),  dim3(256), 0, stream, cb, cbh, e2f, counts);
  hipLaunchKernelGGL(score_kernel,    dim3(1024), dim3(256), 0, stream, z, cbh, e2f, Arow,
                     cand_g, candcnt);
  hipLaunchKernelGGL(rescore_kernel,  dim3(256),  dim3(256), 0, stream, z, cb, e2f, Arow,
                     cand_g, candcnt, idxbuf, counts, out + 8388610, part);
  hipLaunchKernelGGL(fallback_kernel, dim3(256),  dim3(256), 0, stream, z, cb, e2f, Arow,
                     candcnt, idxbuf, counts, out + 8388610, part);
  hipLaunchKernelGGL(gather_kernel,   dim3(1024), dim3(256), 0, stream, cb, idxbuf, out);
  hipLaunchKernelGGL(finalize_kernel, dim3(1),    dim3(256), 0, stream, counts, part, out);
}